// Round 8
// baseline (719.518 us; speedup 1.0000x reference)
//
#include <hip/hip_runtime.h>
#include <hip/hip_bf16.h>

#define NN 20000
#define EE 400000
#define RSBN 0.9999950000374997f   // 1/sqrt(1+1e-5)

typedef __attribute__((ext_vector_type(8))) short short8;
typedef __attribute__((ext_vector_type(8))) unsigned short ushort8;
typedef __attribute__((ext_vector_type(4))) float floatx4;

__device__ __forceinline__ short f2bf(float f) {
  union { float f; unsigned u; } v; v.f = f;
  unsigned r = v.u + 0x7fffu + ((v.u >> 16) & 1u);   // RNE
  return (short)(r >> 16);
}
__device__ __forceinline__ unsigned f2bf2(float x, float y) {   // packed cvt
  union { __hip_bfloat162 h; unsigned u; } v;
  v.h = __float22bfloat162_rn(make_float2(x, y));
  return v.u;
}
__device__ __forceinline__ float bf2f(unsigned short u) {
  union { unsigned u; float f; } v; v.u = ((unsigned)u) << 16;
  return v.f;
}
__device__ __forceinline__ void gl_lds16(const void* g, void* l) {
  __builtin_amdgcn_global_load_lds(
      (const __attribute__((address_space(1))) unsigned*)g,
      (__attribute__((address_space(3))) unsigned*)l, 16, 0, 0);
}
// agent-scope 16B gather: two 8B sc0 loads -> bypass (non-coherent) L1, stay L2-cached.
__device__ __forceinline__ ushort8 ag16(const unsigned short* p) {
  union { ushort8 s; unsigned long long q[2]; } u;
  u.q[0] = __hip_atomic_load((const unsigned long long*)p,     __ATOMIC_RELAXED, __HIP_MEMORY_SCOPE_AGENT);
  u.q[1] = __hip_atomic_load((const unsigned long long*)p + 1, __ATOMIC_RELAXED, __HIP_MEMORY_SCOPE_AGENT);
  return u.s;
}

// ---------------- edge-parser weights -> fragment-layout bf16 + folded consts ----------------
__global__ __launch_bounds__(256) void ewconv_kernel(
    const float* __restrict__ w1, const float* __restrict__ w2,
    const float* __restrict__ g1, const float* __restrict__ be1,
    const float* __restrict__ b1, const float* __restrict__ b2,
    unsigned short* __restrict__ ewf)
{
  int tid = threadIdx.x;
#pragma unroll
  for (int i = 0; i < 16; i++) {
    int idx = i * 256 + tid;
    int k = idx >> 7, n = idx & 127;
    int pos = ((n >> 4) * 64 + (k >> 3) * 16 + (n & 15)) * 8 + (k & 7);
    ewf[pos] = f2bf(w1[idx]);
  }
#pragma unroll
  for (int i = 0; i < 64; i++) {
    int idx = i * 256 + tid;
    int k = idx >> 7, n = idx & 127;
    int pos = (((k >> 5) * 8 + (n >> 4)) * 64 + ((k >> 3) & 3) * 16 + (n & 15)) * 8 + (k & 7);
    ewf[4096 + pos] = f2bf(w2[idx] * g1[k] * RSBN);   // BN scale folded
  }
  float* fb = (float*)(ewf + 20480);
  if (tid < 128) {
    fb[tid] = b1[tid];
    float acc = b2[tid];
    for (int k = 0; k < 128; k++) acc += be1[k] * w2[k * 128 + tid] * g1[k] * RSBN;
    fb[128 + tid] = acc;
  }
}

// ---------------- edge parser + edge weight (bf16 MFMA) ----------------
#define ASP 136
__global__ __launch_bounds__(512, 4) void edge_kernel(
    const float* __restrict__ xin, const int* __restrict__ eidx,
    const unsigned short* __restrict__ ewf,
    float* __restrict__ ew_out,
    float* __restrict__ deg, int* __restrict__ cnt)
{
  __shared__ short wbuf[20992];
  __shared__ short as_s[128 * ASP];

  int tid = threadIdx.x;
  int lane = tid & 63;
  int wv = tid >> 6;
  int l15 = lane & 15;
  int quad = lane >> 4;

#pragma unroll
  for (int i = 0; i < 5; i++)
    gl_lds16(ewf + (i * 512 + tid) * 8, &wbuf[(i * 512 + tid) * 8]);
  if (tid < 64)
    gl_lds16(ewf + (2560 + tid) * 8, &wbuf[(2560 + tid) * 8]);

  const short* w1f = wbuf;
  const short* w2f = wbuf + 4096;

  int rowbase = blockIdx.x * 128 + wv * 16;

  short8 af;
  {
    const float* xp = xin + (size_t)(rowbase + l15) * 32 + quad * 8;
    float4 v0 = *(const float4*)xp;
    float4 v1 = *(const float4*)(xp + 4);
    union { short8 s; unsigned u[4]; } a;
    a.u[0] = f2bf2(v0.x, v0.y); a.u[1] = f2bf2(v0.z, v0.w);
    a.u[2] = f2bf2(v1.x, v1.y); a.u[3] = f2bf2(v1.z, v1.w);
    af = a.s;
  }

  __syncthreads();

  const float* fb = (const float*)(wbuf + 20480);
  float b1j[8], b2j[8];
#pragma unroll
  for (int c = 0; c < 8; c++) {
    b1j[c] = fb[c * 16 + l15];
    b2j[c] = fb[128 + c * 16 + l15];
  }

  floatx4 acc[8];
#pragma unroll
  for (int c = 0; c < 8; c++) {
    floatx4 z = {b1j[c], b1j[c], b1j[c], b1j[c]};
    acc[c] = __builtin_amdgcn_mfma_f32_16x16x32_bf16(
        af, *(const short8*)&w1f[(c * 64 + lane) * 8], z, 0, 0, 0);
  }

#pragma unroll
  for (int c = 0; c < 8; c++)
#pragma unroll
    for (int r = 0; r < 4; r += 2) {
      unsigned pk = f2bf2(fmaxf(acc[c][r], 0.f), fmaxf(acc[c][r + 1], 0.f));
      int base = (wv * 16 + quad * 4 + r) * ASP + c * 16 + l15;
      as_s[base] = (short)(pk & 0xffff);
      as_s[base + ASP] = (short)(pk >> 16);
    }

  floatx4 acc2[8];
#pragma unroll
  for (int c = 0; c < 8; c++) acc2[c] = (floatx4){b2j[c], b2j[c], b2j[c], b2j[c]};
#pragma unroll
  for (int s = 0; s < 4; s++) {
    short8 a2 = *(const short8*)&as_s[(wv * 16 + l15) * ASP + s * 32 + quad * 8];
#pragma unroll
    for (int c = 0; c < 8; c++) {
      short8 bf = *(const short8*)&w2f[((s * 8 + c) * 64 + lane) * 8];
      acc2[c] = __builtin_amdgcn_mfma_f32_16x16x32_bf16(a2, bf, acc2[c], 0, 0, 0);
    }
  }

  float p[2], qq[2], rr[2];
#pragma unroll
  for (int i = 0; i < 2; i++) { p[i] = 0.f; qq[i] = 0.f; rr[i] = 0.f; }
#pragma unroll
  for (int c = 0; c < 8; c++)
#pragma unroll
    for (int i = 0; i < 2; i++) {
      float hx = acc2[c][2 * i];
      float hy = acc2[c][2 * i + 1];
      p[i]  += hx * hy;
      qq[i] += hx * hx;
      rr[i] += hy * hy;
    }
#pragma unroll
  for (int m = 1; m < 16; m <<= 1)
#pragma unroll
    for (int i = 0; i < 2; i++) {
      p[i]  += __shfl_xor(p[i], m, 64);
      qq[i] += __shfl_xor(qq[i], m, 64);
      rr[i] += __shfl_xor(rr[i], m, 64);
    }
  if (l15 == 0) {
#pragma unroll
    for (int i = 0; i < 2; i++) {
      int row = rowbase + quad * 4 + 2 * i;
      int e = row >> 1;
      float n1 = fmaxf(sqrtf(qq[i]), 1e-8f);
      float n2 = fmaxf(sqrtf(rr[i]), 1e-8f);
      float w = (p[i] / (n1 * n2) + 1.f) * 0.5f;
      ew_out[e] = w;
      atomicAdd(deg + eidx[e], w);
      atomicAdd(cnt + eidx[EE + e], 1);
    }
  }
}

// ---------------- features fp32 -> bf16 ----------------
__global__ __launch_bounds__(256) void fconv_kernel(const float* __restrict__ src,
                                                    unsigned short* __restrict__ dst) {
  size_t i = ((size_t)blockIdx.x * 256 + threadIdx.x) * 8;
  float4 a = *(const float4*)(src + i);
  float4 b = *(const float4*)(src + i + 4);
  union { ushort8 s; unsigned u[4]; } o;
  o.u[0] = f2bf2(a.x, a.y); o.u[1] = f2bf2(a.z, a.w);
  o.u[2] = f2bf2(b.x, b.y); o.u[3] = f2bf2(b.z, b.w);
  *(ushort8*)(dst + i) = o.s;
}

// ---------------- weights: transpose 256x256 chunks, fp32 -> bf16, Cheb fold ----------------
// cheb layer l: chunk0 = W0 - W2, chunk1 = W1, chunk2 = 2*W2  (Tx2 identity folded out)
__global__ __launch_bounds__(256) void wconv_kernel(
    const float* __restrict__ cheb_w, const float* __restrict__ cls_w1,
    unsigned short* __restrict__ wtc, unsigned short* __restrict__ clsT)
{
  __shared__ unsigned short tile[64][80];
  int z = blockIdx.z;
  const float* srcA; const float* srcB = nullptr; float scale = 1.f;
  unsigned short* dst; int ldk;
  if (z < 12) {
    int l = z / 3, c = z % 3;
    srcA = cheb_w + (size_t)z * 65536;
    if (c == 0) srcB = cheb_w + (size_t)(l * 3 + 2) * 65536;   // W0 - W2
    if (c == 2) scale = 2.f;                                   // 2*W2
    dst = wtc + (size_t)l * 196608 + c * 256;
    ldk = 768;
  } else {
    int c = z - 12;
    srcA = cls_w1 + (size_t)c * 65536;
    dst = clsT + c * 256;
    ldk = 1024;
  }
  int t = threadIdx.x;
  int k0 = blockIdx.x * 64, n0 = blockIdx.y * 64;
#pragma unroll
  for (int pass = 0; pass < 4; pass++) {
    int kk = pass * 16 + (t >> 4);
    int nl = (t & 15) * 4;
    size_t off = (size_t)(k0 + kk) * 256 + n0 + nl;
    float4 v = *(const float4*)(srcA + off);
    if (srcB) {
      float4 u = *(const float4*)(srcB + off);
      v.x -= u.x; v.y -= u.y; v.z -= u.z; v.w -= u.w;
    } else if (scale != 1.f) {
      v.x *= scale; v.y *= scale; v.z *= scale; v.w *= scale;
    }
    tile[nl + 0][kk] = f2bf(v.x);
    tile[nl + 1][kk] = f2bf(v.y);
    tile[nl + 2][kk] = f2bf(v.z);
    tile[nl + 3][kk] = f2bf(v.w);
  }
  __syncthreads();
  int nl = t >> 2, kc = (t & 3) * 16;
  ushort8 v0 = *(const ushort8*)&tile[nl][kc];
  ushort8 v1 = *(const ushort8*)&tile[nl][kc + 8];
  unsigned short* dp = dst + (size_t)(n0 + nl) * ldk + k0 + kc;
  *(ushort8*)dp = v0;
  *(ushort8*)(dp + 8) = v1;
}

// ---------------- degree -> D^-1/2 ----------------
__global__ void dis_kernel(const float* __restrict__ deg, float* __restrict__ dis) {
  int i = blockIdx.x * 256 + threadIdx.x;
  if (i < NN) {
    float d = deg[i];
    dis[i] = d > 0.f ? 1.f / sqrtf(fmaxf(d, 1e-30f)) : 0.f;
  }
}

// ---------------- exclusive scan of in-degree counts (padded to x4) ----------------
__global__ __launch_bounds__(1024) void scan_kernel(const int* __restrict__ cnt, int* __restrict__ ptr) {
  __shared__ int sums[1024];
  int tid = threadIdx.x;
  const int n = NN;
  const int chunk = (n + 1023) / 1024;
  int base = tid * chunk;
  int s = 0;
  for (int i = 0; i < chunk; i++) {
    int idx = base + i;
    if (idx < n) s += (cnt[idx] + 3) & ~3;
  }
  sums[tid] = s;
  __syncthreads();
  for (int off = 1; off < 1024; off <<= 1) {
    int v = (tid >= off) ? sums[tid - off] : 0;
    __syncthreads();
    sums[tid] += v;
    __syncthreads();
  }
  int run = (tid == 0) ? 0 : sums[tid - 1];
  for (int i = 0; i < chunk; i++) {
    int idx = base + i;
    if (idx < n) { ptr[idx] = run; run += (cnt[idx] + 3) & ~3; }
  }
  if (tid == 1023) ptr[n] = run;
}

// ---------------- CSR fill (pad slots pre-zeroed) ----------------
__global__ void fill_kernel(const int* __restrict__ eidx, const float* __restrict__ ew,
                            const float* __restrict__ dis, const int* __restrict__ ptr,
                            int* __restrict__ fill, int* __restrict__ cidx, float* __restrict__ cval) {
  int e = blockIdx.x * 256 + threadIdx.x;
  if (e < EE) {
    int r = eidx[e], c = eidx[EE + e];
    float nv = -dis[r] * ew[e] * dis[c];
    int pos = ptr[c] + atomicAdd(&fill[c], 1);
    cidx[pos] = r;
    cval[pos] = nv;
  }
}

// ---------------- sparse prop (bf16, XCD-sliced, L1-bypass gathers) ----------------
// y[c] = sum val*x[row]. Column slice = (blockIdx&7)>>1 (64ch = 128B line).
// 8 lanes per node. Segments padded to x4. Gathers are agent-scope (sc0): skip the
// ~1%-hit L1 (frees MSHRs), stay L2-resident. 2-stage pipeline retained.
__global__ __launch_bounds__(256) void prop_kernel(
    const unsigned short* __restrict__ x, int ldx,
    const int* __restrict__ cidx, const float* __restrict__ cval,
    const int* __restrict__ ptr,
    unsigned short* __restrict__ y, int ldy)
{
  int sliceid = blockIdx.x & 7;
  int colslice = sliceid >> 1;                       // 0..3
  int chunk = (blockIdx.x >> 3) * 2 + (sliceid & 1); // 0..625
  int c = chunk * 32 + (threadIdx.x >> 3);
  if (c >= NN) return;
  int d = colslice * 64 + (threadIdx.x & 7) * 8;
  int p0 = ptr[c], p1 = ptr[c + 1];
  float a[8] = {0.f, 0.f, 0.f, 0.f, 0.f, 0.f, 0.f, 0.f};
  if (p0 < p1) {
    int4 r4 = *(const int4*)(cidx + p0);
    float4 w4 = *(const float4*)(cval + p0);
    ushort8 v0 = ag16(x + (size_t)r4.x * ldx + d);
    ushort8 v1 = ag16(x + (size_t)r4.y * ldx + d);
    ushort8 v2 = ag16(x + (size_t)r4.z * ldx + d);
    ushort8 v3 = ag16(x + (size_t)r4.w * ldx + d);
    for (int p = p0 + 4; p < p1; p += 4) {
      int4 r4n = *(const int4*)(cidx + p);
      float4 w4n = *(const float4*)(cval + p);
      ushort8 n0 = ag16(x + (size_t)r4n.x * ldx + d);
      ushort8 n1 = ag16(x + (size_t)r4n.y * ldx + d);
      ushort8 n2 = ag16(x + (size_t)r4n.z * ldx + d);
      ushort8 n3 = ag16(x + (size_t)r4n.w * ldx + d);
#pragma unroll
      for (int j = 0; j < 8; j++)
        a[j] += w4.x * bf2f(v0[j]) + w4.y * bf2f(v1[j]) + w4.z * bf2f(v2[j]) + w4.w * bf2f(v3[j]);
      w4 = w4n; v0 = n0; v1 = n1; v2 = n2; v3 = n3;
    }
#pragma unroll
    for (int j = 0; j < 8; j++)
      a[j] += w4.x * bf2f(v0[j]) + w4.y * bf2f(v1[j]) + w4.z * bf2f(v2[j]) + w4.w * bf2f(v3[j]);
  }
  union { ushort8 s; unsigned u[4]; } o;
#pragma unroll
  for (int j = 0; j < 8; j += 2)
    o.u[j >> 1] = f2bf2(a[j], a[j + 1]);
  *(ushort8*)(y + (size_t)c * ldy + d) = o.s;
}

// ---------------- bf16 MFMA GEMM: C = post( sum_c A_c @ B_c ) ----------------
__global__ __launch_bounds__(256, 4) void mgemm_kernel(
    const unsigned short* A0, const unsigned short* A1,
    const unsigned short* A2, const unsigned short* A3,
    int l0, int l1, int l2, int l3, int nchunks,
    const unsigned short* __restrict__ BT, int ldbt,
    unsigned short* __restrict__ Cb, float* __restrict__ Cf, int ldc, int M,
    const float* __restrict__ bias, const float* __restrict__ bng,
    const float* __restrict__ bnb)
{
  __shared__ short As[4 * 64 * 8];
  __shared__ short Bs[4 * 128 * 8];
  int tid = threadIdx.x;
  int lane = tid & 63;
  int wv = tid >> 6;
  int l15 = lane & 15, quad = lane >> 4;
  int wr = wv >> 1, wc = wv & 1;
  int m0 = blockIdx.x * 64, n0 = blockIdx.y * 128;

  const unsigned short* Ap[4] = {A0, A1, A2, A3};
  int Al[4] = {l0, l1, l2, l3};

  int arow = tid & 63, ac = tid >> 6;
  int brow = tid & 127, bc = tid >> 7;

  floatx4 acc[2][4];
#pragma unroll
  for (int mi = 0; mi < 2; mi++)
#pragma unroll
    for (int nj = 0; nj < 4; nj++) acc[mi][nj] = (floatx4){0.f, 0.f, 0.f, 0.f};

  for (int c = 0; c < nchunks; c++) {
    const unsigned short* Abase = Ap[c] + (size_t)(m0 + arow) * Al[c] + ac * 8;
    const unsigned short* Bbase = BT + (size_t)(n0 + brow) * ldbt + c * 256 + bc * 8;
#pragma unroll 1
    for (int kb = 0; kb < 256; kb += 32) {
      __syncthreads();
      gl_lds16(Abase + kb, &As[tid * 8]);
      gl_lds16(Bbase + kb, &Bs[tid * 8]);
      gl_lds16(Bbase + 16 + kb, &Bs[(tid + 256) * 8]);
      __syncthreads();
      short8 af[2], bfv[4];
#pragma unroll
      for (int mi = 0; mi < 2; mi++)
        af[mi] = *(const short8*)&As[(quad * 64 + wr * 32 + mi * 16 + l15) * 8];
#pragma unroll
      for (int nj = 0; nj < 4; nj++)
        bfv[nj] = *(const short8*)&Bs[(quad * 128 + wc * 64 + nj * 16 + l15) * 8];
#pragma unroll
      for (int nj = 0; nj < 4; nj++)
#pragma unroll
        for (int mi = 0; mi < 2; mi++)
          acc[mi][nj] = __builtin_amdgcn_mfma_f32_16x16x32_bf16(af[mi], bfv[nj], acc[mi][nj], 0, 0, 0);
    }
  }

  if (Cb) {
#pragma unroll
    for (int mi = 0; mi < 2; mi++)
#pragma unroll
      for (int r = 0; r < 4; r++) {
        int row = m0 + wr * 32 + mi * 16 + quad * 4 + r;
        if (row < M) {
#pragma unroll
          for (int nj = 0; nj < 4; nj++) {
            int col = n0 + wc * 64 + nj * 16 + l15;
            Cb[(size_t)row * ldc + col] = (unsigned short)f2bf(fmaxf(acc[mi][nj][r], 0.f));
          }
        }
      }
  } else {
    float bs[4], g[4], bb[4];
#pragma unroll
    for (int nj = 0; nj < 4; nj++) {
      int col = n0 + wc * 64 + nj * 16 + l15;
      bs[nj] = bias[col]; g[nj] = bng[col] * RSBN; bb[nj] = bnb[col];
    }
#pragma unroll
    for (int mi = 0; mi < 2; mi++)
#pragma unroll
      for (int r = 0; r < 4; r++) {
        int row = m0 + wr * 32 + mi * 16 + quad * 4 + r;
        if (row < M) {
#pragma unroll
          for (int nj = 0; nj < 4; nj++) {
            int col = n0 + wc * 64 + nj * 16 + l15;
            float v = fmaxf(acc[mi][nj][r] + bs[nj], 0.f) * g[nj] + bb[nj];
            Cf[(size_t)row * ldc + col] = v;
          }
        }
      }
  }
}

// ---------------- final 256x2 matvec per node ----------------
__global__ __launch_bounds__(256) void logit_kernel(
    const float* __restrict__ z, const float* __restrict__ w2,
    const float* __restrict__ b2, float* __restrict__ out)
{
  int node = blockIdx.x * 4 + (threadIdx.x >> 6);
  if (node >= NN) return;
  int lane = threadIdx.x & 63;
  int k = lane * 4;
  float4 zv = *(const float4*)(z + (size_t)node * 256 + k);
  float4 wa = *(const float4*)(w2 + k * 2);
  float4 wb = *(const float4*)(w2 + k * 2 + 4);
  float a0 = zv.x * wa.x + zv.y * wa.z + zv.z * wb.x + zv.w * wb.z;
  float a1 = zv.x * wa.y + zv.y * wa.w + zv.z * wb.y + zv.w * wb.w;
#pragma unroll
  for (int m = 32; m >= 1; m >>= 1) {
    a0 += __shfl_xor(a0, m, 64);
    a1 += __shfl_xor(a1, m, 64);
  }
  if (lane == 0) {
    out[(size_t)node * 2]     = a0 + b2[0];
    out[(size_t)node * 2 + 1] = a1 + b2[1];
  }
}

extern "C" void kernel_launch(void* const* d_in, const int* in_sizes, int n_in,
                              void* d_out, int out_size, void* d_ws, size_t ws_size,
                              hipStream_t stream) {
  const float* features = (const float*)d_in[0];
  const int*   eidx     = (const int*)d_in[1];
  const float* xin      = (const float*)d_in[2];
  const float* cheb_w   = (const float*)d_in[3];
  const float* en_w1    = (const float*)d_in[4];
  const float* en_b1    = (const float*)d_in[5];
  const float* en_g1    = (const float*)d_in[6];
  const float* en_be1   = (const float*)d_in[7];
  const float* en_w2    = (const float*)d_in[8];
  const float* en_b2    = (const float*)d_in[9];
  const float* cls_w1   = (const float*)d_in[10];
  const float* cls_b1   = (const float*)d_in[11];
  const float* cls_g    = (const float*)d_in[12];
  const float* cls_b    = (const float*)d_in[13];
  const float* cls_w2   = (const float*)d_in[14];
  const float* cls_b2   = (const float*)d_in[15];
  float* out = (float*)d_out;

  char* ws = (char*)d_ws;
  size_t off = 0;
  auto alloc = [&](size_t bytes) -> void* {
    void* p = ws + off;
    off += (bytes + 255) & ~(size_t)255;
    return p;
  };
  const int CSRN = EE + 4 * NN;   // padded CSR capacity
  float* deg  = (float*)alloc((size_t)NN * 4);
  int*   cnt  = (int*)  alloc((size_t)NN * 4);
  int*   fil  = (int*)  alloc((size_t)NN * 4);
  float* cval = (float*)alloc((size_t)CSRN * 4);
  int*   cidx = (int*)  alloc((size_t)CSRN * 4);
  size_t zero_len = off;                       // deg+cnt+fil+cval+cidx zeroed
  float* dis  = (float*)alloc((size_t)NN * 4);
  int*   ptr  = (int*)  alloc((size_t)(NN + 1) * 4);
  unsigned short* featb = (unsigned short*)alloc((size_t)NN * 256 * 2);
  unsigned short* Tx1   = (unsigned short*)alloc((size_t)NN * 256 * 2);
  unsigned short* Tx2   = (unsigned short*)alloc((size_t)NN * 256 * 2);
  unsigned short* jk    = (unsigned short*)alloc((size_t)NN * 1024 * 2);
  float* zbuf = (float*)alloc((size_t)NN * 256 * 4);
  unsigned short* wtc   = (unsigned short*)alloc((size_t)4 * 196608 * 2);
  unsigned short* clsT  = (unsigned short*)alloc((size_t)256 * 1024 * 2);
  unsigned short* ewf   = (unsigned short*)alloc((size_t)20992 * 2);
  alloc(262144);   // overread pad for GEMM tail blocks

  float* ew = out + (size_t)NN * 2;   // edge-weight output doubles as scratch

  hipMemsetAsync(deg, 0, zero_len, stream);

  ewconv_kernel<<<1, 256, 0, stream>>>(en_w1, en_w2, en_g1, en_be1, en_b1, en_b2, ewf);
  edge_kernel<<<6250, 512, 0, stream>>>(xin, eidx, ewf, ew, deg, cnt);
  fconv_kernel<<<2500, 256, 0, stream>>>(features, featb);
  wconv_kernel<<<dim3(4, 4, 16), 256, 0, stream>>>(cheb_w, cls_w1, wtc, clsT);
  dis_kernel<<<(NN + 255) / 256, 256, 0, stream>>>(deg, dis);
  scan_kernel<<<1, 1024, 0, stream>>>(cnt, ptr);
  fill_kernel<<<(EE + 255) / 256, 256, 0, stream>>>(eidx, ew, dis, ptr, fil, cidx, cval);

  dim3 ggrid(313, 2);
  for (int i = 0; i < 4; i++) {
    const unsigned short* x = (i == 0) ? featb : (jk + (size_t)(i - 1) * 256);
    int ldx = (i == 0) ? 256 : 1024;
    prop_kernel<<<2504, 256, 0, stream>>>(x, ldx, cidx, cval, ptr, Tx1, 256);
    prop_kernel<<<2504, 256, 0, stream>>>(Tx1, 256, cidx, cval, ptr, Tx2, 256);
    // h = relu( x(W0-W2) + Tx1*W1 + (P*Tx1)*(2W2) )  — folding done in wconv
    mgemm_kernel<<<ggrid, 256, 0, stream>>>(x, Tx1, Tx2, nullptr, ldx, 256, 256, 0, 3,
                                            wtc + (size_t)i * 196608, 768,
                                            jk + (size_t)i * 256, nullptr, 1024, NN,
                                            nullptr, nullptr, nullptr);
  }

  mgemm_kernel<<<ggrid, 256, 0, stream>>>(jk, jk + 256, jk + 512, jk + 768,
                                          1024, 1024, 1024, 1024, 4, clsT, 1024,
                                          nullptr, zbuf, 256, NN,
                                          cls_b1, cls_g, cls_b);
  logit_kernel<<<NN / 4, 256, 0, stream>>>(zbuf, cls_w2, cls_b2, out);
}